// Round 4
// baseline (24.942 us; speedup 1.0000x reference)
//
#include <hip/hip_runtime.h>
#include <hip/hip_bf16.h>

#define NPOS   1024
#define NBATCH 4
#define BT     64    // output tile (both dims)
#define LDT    136   // padded LDS leading dim in halves (K=128 + 8)

typedef _Float16 half8  __attribute__((ext_vector_type(8)));
typedef _Float16 half2x __attribute__((ext_vector_type(2)));
typedef float    floatx4 __attribute__((ext_vector_type(4)));

#define INV2PI 0.15915494309189535f

// ABLATION ROUND: kernel body identical to R3. kernel_launch launches it
// 3x back-to-back (idempotent: same values written each time) to split
// fixed graph-replay overhead from true kernel time:
//   dur(R3) = oh + k ; dur(R4) = oh + 3k.
__global__ __launch_bounds__(256, 4)
void fourier_bias_kernel(const float* __restrict__ frac,
                         const float* __restrict__ Wv,
                         const float* __restrict__ bv,
                         const float* __restrict__ av,
                         float* __restrict__ out) {
    __shared__ _Float16 sA[BT][LDT];
    __shared__ _Float16 sB[BT][LDT];

    const int tid = threadIdx.x;
    const int bz  = blockIdx.z;           // batch
    const int ti  = blockIdx.y * BT;      // output row tile origin (i)
    const int tj  = blockIdx.x * BT;      // output col tile origin (j)

    // ---- phase 1: fill feature tiles in LDS ----
    const int   f      = tid & 63;
    const int   rt     = tid >> 6;        // 0..3
    const float wf_rev = Wv[f] * (10.0f * INV2PI);
    const float bf_rev = bv[f] * INV2PI;
    const float af     = av[f];
    const float* fb = frac + bz * NPOS;

    #pragma unroll
    for (int t = 0; t < 16; ++t) {
        const int row = rt + t * 4;       // rows rt, rt+4, ..., rt+60
        const float xi = fb[ti + row];    // wave-uniform
        const float ai = xi * wf_rev;
        half2x pa;
        pa[0] = (_Float16)__builtin_amdgcn_cosf(ai);
        pa[1] = (_Float16)__builtin_amdgcn_sinf(ai);
        *reinterpret_cast<half2x*>(&sA[row][2 * f]) = pa;   // 4B-aligned
        const float xj = fb[tj + row];
        const float aj = __builtin_fmaf(xj, wf_rev, bf_rev);
        half2x pb;
        pb[0] = (_Float16)(af * __builtin_amdgcn_cosf(aj));
        pb[1] = (_Float16)(af * __builtin_amdgcn_sinf(aj));
        *reinterpret_cast<half2x*>(&sB[row][2 * f]) = pb;
    }
    __syncthreads();

    // ---- phase 2: 64x64 GEMM, K=128, f16 MFMA, fp32 accum ----
    const int lane = tid & 63;
    const int wid  = tid >> 6;
    const int wr   = (wid >> 1) * 32;
    const int wc   = (wid & 1) * 32;

    const int lrow = lane & 15;           // fragment row within 16
    const int lkb  = lane >> 4;           // k sub-block (8 halves each)

    floatx4 acc[2][2];
    #pragma unroll
    for (int m = 0; m < 2; ++m)
        #pragma unroll
        for (int n = 0; n < 2; ++n)
            acc[m][n] = (floatx4){0.f, 0.f, 0.f, 0.f};

    #pragma unroll
    for (int t = 0; t < 4; ++t) {         // 4 K-steps of 32
        const int k = t * 32 + lkb * 8;
        half8 afr[2], bfr[2];
        #pragma unroll
        for (int m = 0; m < 2; ++m)
            afr[m] = *reinterpret_cast<const half8*>(&sA[wr + m * 16 + lrow][k]);
        #pragma unroll
        for (int n = 0; n < 2; ++n)
            bfr[n] = *reinterpret_cast<const half8*>(&sB[wc + n * 16 + lrow][k]);
        #pragma unroll
        for (int m = 0; m < 2; ++m)
            #pragma unroll
            for (int n = 0; n < 2; ++n)
                acc[m][n] = __builtin_amdgcn_mfma_f32_16x16x32_f16(
                    afr[m], bfr[n], acc[m][n], 0, 0, 0);
    }

    // ---- epilogue: C/D layout col = lane&15, row = (lane>>4)*4 + reg ----
    const int col  = lane & 15;
    const int row4 = (lane >> 4) * 4;
    #pragma unroll
    for (int m = 0; m < 2; ++m) {
        #pragma unroll
        for (int n = 0; n < 2; ++n) {
            const size_t gi = (size_t)(ti + wr + m * 16 + row4);
            const size_t gj = (size_t)(tj + wc + n * 16 + col);
            float* o = out + ((size_t)bz * NPOS + gi) * NPOS + gj;
            #pragma unroll
            for (int r = 0; r < 4; ++r)
                o[(size_t)r * NPOS] = acc[m][n][r];
        }
    }
}

extern "C" void kernel_launch(void* const* d_in, const int* in_sizes, int n_in,
                              void* d_out, int out_size, void* d_ws, size_t ws_size,
                              hipStream_t stream) {
    const float* frac = (const float*)d_in[0];  // [4,1024]
    const float* Wv   = (const float*)d_in[1];  // [1,64]
    const float* bv   = (const float*)d_in[2];  // [64]
    const float* av   = (const float*)d_in[3];  // [64]
    float* out = (float*)d_out;                 // [4,1024,1024]

    dim3 grid(NPOS / BT, NPOS / BT, NBATCH);
    // 3x identical launches (idempotent writes) — overhead/kernel ablation.
    fourier_bias_kernel<<<grid, dim3(256), 0, stream>>>(frac, Wv, bv, av, out);
    fourier_bias_kernel<<<grid, dim3(256), 0, stream>>>(frac, Wv, bv, av, out);
    fourier_bias_kernel<<<grid, dim3(256), 0, stream>>>(frac, Wv, bv, av, out);
}

// Round 5
// 11.180 us; speedup vs baseline: 2.2309x; 2.2309x over previous
//
#include <hip/hip_runtime.h>
#include <hip/hip_bf16.h>

#define NPOS   1024
#define NBATCH 4
#define RT     128   // output region per WG (both dims) = 2x2 tiles of 64
#define LDT    136   // sA/sB leading dim in halves (K=128 + 8 pad)
#define CLD    68    // bounce leading dim in floats (64 + 4 pad, 16B-aligned rows)

typedef _Float16 half8  __attribute__((ext_vector_type(8)));
typedef _Float16 half2x __attribute__((ext_vector_type(2)));
typedef float    floatx4 __attribute__((ext_vector_type(4)));

#define INV2PI 0.15915494309189535f

// out[b,i,j] = sum_f a_f*cos(10*(x_j-x_i)*w_f + b_f) = <A[i,:], B[j,:]>, K=128
// A[i,2f]=cos(t_i) A[i,2f+1]=sin(t_i); B[j,2f]=a_f cos(t_j+b_f) B[j,2f+1]=a_f sin(..)
// (K order = (cos,sin) interleaved; dot product invariant under K-permutation.)
// Trig in revolutions (v_sin/v_cos native); |args| <= ~1.8 rev, no reduction.
//
// R5: 128x128 region/WG (256 WGs, 1/CU) -> trig halved vs R3 (4.2M sincos).
// Per 16-row m-block: MFMA -> per-wave LDS bounce transpose -> nontemporal
// dwordx4 stores (full 128B lines), so stores stream throughout the kernel
// instead of piling into a lockstep end-of-kernel drain.
__global__ __launch_bounds__(256, 1)
void fourier_bias_kernel(const float* __restrict__ frac,
                         const float* __restrict__ Wv,
                         const float* __restrict__ bv,
                         const float* __restrict__ av,
                         float* __restrict__ out) {
    __shared__ _Float16 sA[RT][LDT];      // 34.8 KB
    __shared__ _Float16 sB[RT][LDT];      // 34.8 KB
    __shared__ float    sC[4][16][CLD];   // 17.4 KB  per-wave bounce slices
    __shared__ float    sXA[RT], sXB[RT]; // 1 KB

    const int tid = threadIdx.x;
    const int bz  = blockIdx.z;
    const int ti  = blockIdx.y * RT;
    const int tj  = blockIdx.x * RT;

    // ---- phase 0: preload frac rows (one coalesced load) ----
    const float* fb = frac + bz * NPOS;
    if (tid < 128) sXA[tid]       = fb[ti + tid];
    else           sXB[tid - 128] = fb[tj + (tid - 128)];

    const int   f      = tid & 63;
    const int   rt4    = tid >> 6;        // 0..3
    const float wf_rev = Wv[f] * (10.0f * INV2PI);
    const float bf_rev = bv[f] * INV2PI;
    const float af     = av[f];
    __syncthreads();

    // ---- phase 1: trig fill of A/B feature tiles ----
    #pragma unroll
    for (int t = 0; t < 32; ++t) {
        const int row = rt4 + t * 4;      // rows rt4, rt4+4, ..., rt4+124
        const float ai = sXA[row] * wf_rev;
        half2x pa;
        pa[0] = (_Float16)__builtin_amdgcn_cosf(ai);
        pa[1] = (_Float16)__builtin_amdgcn_sinf(ai);
        *reinterpret_cast<half2x*>(&sA[row][2 * f]) = pa;
        const float aj = __builtin_fmaf(sXB[row], wf_rev, bf_rev);
        half2x pb;
        pb[0] = (_Float16)(af * __builtin_amdgcn_cosf(aj));
        pb[1] = (_Float16)(af * __builtin_amdgcn_sinf(aj));
        *reinterpret_cast<half2x*>(&sB[row][2 * f]) = pb;
    }
    __syncthreads();

    // ---- phase 2: per-wave 64x64 quadrant, K=128, f16 MFMA ----
    const int lane = tid & 63;
    const int wid  = tid >> 6;
    const int wr   = (wid >> 1) * 64;     // wave row origin in region
    const int wc   = (wid & 1) * 64;      // wave col origin in region
    const int lrow = lane & 15;
    const int lkb  = lane >> 4;           // k sub-block (8 halves)
    const int rhi  = (lane >> 4) * 4;     // C/D row group

    // hoist all B fragments (16 x half8 = 64 VGPRs)
    half8 bfr[4][4];
    #pragma unroll
    for (int t = 0; t < 4; ++t)
        #pragma unroll
        for (int n = 0; n < 4; ++n)
            bfr[t][n] = *reinterpret_cast<const half8*>(
                &sB[wc + n * 16 + lrow][t * 32 + lkb * 8]);

    #pragma unroll
    for (int m = 0; m < 4; ++m) {         // 16-row m-blocks: compute->store
        floatx4 acc[4];
        #pragma unroll
        for (int n = 0; n < 4; ++n) acc[n] = (floatx4){0.f, 0.f, 0.f, 0.f};

        #pragma unroll
        for (int t = 0; t < 4; ++t) {
            const half8 afr = *reinterpret_cast<const half8*>(
                &sA[wr + m * 16 + lrow][t * 32 + lkb * 8]);
            #pragma unroll
            for (int n = 0; n < 4; ++n)
                acc[n] = __builtin_amdgcn_mfma_f32_16x16x32_f16(
                    afr, bfr[t][n], acc[n], 0, 0, 0);
        }

        // bounce transpose through this wave's private sC slice
        // (same-wave LDS ops are in-order; compiler inserts lgkmcnt waits)
        #pragma unroll
        for (int n = 0; n < 4; ++n)
            #pragma unroll
            for (int r = 0; r < 4; ++r)
                sC[wid][rhi + r][n * 16 + lrow] = acc[n][r];

        // each thread now stores one float4 of 4 rows (full 128B lines)
        #pragma unroll
        for (int q = 0; q < 4; ++q) {
            const int row16 = q * 4 + (lane >> 4);
            const int c4    = lrow * 4;
            const floatx4 v = *reinterpret_cast<const floatx4*>(&sC[wid][row16][c4]);
            const size_t gi = (size_t)(ti + wr + m * 16 + row16);
            const size_t gj = (size_t)(tj + wc + c4);
            __builtin_nontemporal_store(
                v, reinterpret_cast<floatx4*>(out + ((size_t)bz * NPOS + gi) * NPOS + gj));
        }
    }
}

extern "C" void kernel_launch(void* const* d_in, const int* in_sizes, int n_in,
                              void* d_out, int out_size, void* d_ws, size_t ws_size,
                              hipStream_t stream) {
    const float* frac = (const float*)d_in[0];  // [4,1024]
    const float* Wv   = (const float*)d_in[1];  // [1,64]
    const float* bv   = (const float*)d_in[2];  // [64]
    const float* av   = (const float*)d_in[3];  // [64]
    float* out = (float*)d_out;                 // [4,1024,1024]

    dim3 grid(NPOS / RT, NPOS / RT, NBATCH);    // 8 x 8 x 4 = 256 WGs
    fourier_bias_kernel<<<grid, dim3(256), 0, stream>>>(frac, Wv, bv, av, out);
}